// Round 10
// baseline (5028.786 us; speedup 1.0000x reference)
//
#include <hip/hip_runtime.h>
#include <hip/hip_fp16.h>
#include <math.h>

#define TT 50
#define BB 256
#define HH 256
#define MSZ 256
#define MDM 64
#define NRD 4
#define NCL 5
#define GAMMA_ 0.95f
#define EPS_ 1e-8f

typedef unsigned int uint;

__device__ __forceinline__ float sigf(float x){ return 1.f/(1.f + expf(-x)); }

typedef _Float16 h2_t __attribute__((ext_vector_type(2)));

#if __has_builtin(__builtin_amdgcn_fdot2)
__device__ __forceinline__ float dot2(uint w, uint v, float c){
  return __builtin_amdgcn_fdot2(__builtin_bit_cast(h2_t, w),
                                __builtin_bit_cast(h2_t, v), c, false);
}
#else
__device__ __forceinline__ float dot2(uint w, uint v, float c){
  h2_t a = __builtin_bit_cast(h2_t, w), b = __builtin_bit_cast(h2_t, v);
  c = fmaf((float)a.x, (float)b.x, c);
  return fmaf((float)a.y, (float)b.y, c);
}
#endif

__device__ __forceinline__ uint pkh(float a, float b){
  uint lo = (uint)__half_as_ushort(__float2half_rn(a));
  uint hi = (uint)__half_as_ushort(__float2half_rn(b));
  return lo | (hi << 16);
}

// ---------------- K0: pack recurrent weights to f16 k-pairs (unit-major gate cols) ----------------
__global__ __launch_bounds__(256) void k_pack(
  const float* __restrict__ Wih, const float* __restrict__ Whh,
  const float* __restrict__ Wkp, uint* __restrict__ Wpk,
  uint* __restrict__ Wkpu, float4* __restrict__ Wa4)
{
  int i = blockIdx.x*256 + threadIdx.x;
  if (i < 262144){
    int kp = i >> 10, c = i & 1023;
    int u = c >> 2, g = c & 3;
    int cs = g*256 + u;
    int k0 = 2*kp, k1 = k0 + 1;
    float v0 = (k0 < 256) ? Wih[(405+k0)*1024 + cs] : Whh[(k0-256)*1024 + cs];
    float v1 = (k1 < 256) ? Wih[(405+k1)*1024 + cs] : Whh[(k1-256)*1024 + cs];
    Wpk[kp*1024 + c] = pkh(v0, v1);
  } else if (i < 294912){
    int j = i - 262144; int ip = j >> 8, jj = j & 255;
    Wkpu[ip*256 + jj] = pkh(Wkp[(2*ip)*260 + jj], Wkp[(2*ip+1)*260 + jj]);
  } else if (i < 295168){
    int j = i - 294912;
    const float* Wa = Wkp + j*260 + 256;
    Wa4[j] = make_float4(Wa[0], Wa[1], Wa[2], Wa[3]);
  }
}

// ---------------- K0b: pack W_ih[:400] to f16 k-pairs in PERMUTED col space; blP/offP ----------------
__global__ __launch_bounds__(256) void k_pack2(
  const float* __restrict__ Wih, const float* __restrict__ bl,
  uint* __restrict__ Wxpk, float* __restrict__ blP, float* __restrict__ offP)
{
  int i = blockIdx.x*256 + threadIdx.x;
  if (i < 204800){
    int kp = i >> 10, c = i & 1023;
    int cs = (c & 3)*256 + (c >> 2);
    Wxpk[i] = pkh(Wih[(2*kp)*1024 + cs], Wih[(2*kp+1)*1024 + cs]);
  } else if (i < 205824){
    int c = i - 204800;
    int cs = (c & 3)*256 + (c >> 2);
    blP[c] = bl[cs];
  } else if (i < 210944){
    int j = i - 205824;
    int cls = j >> 10, c = j & 1023;
    int cs = (c & 3)*256 + (c >> 2);
    offP[j] = Wih[(400+cls)*1024 + cs];
  }
}

// ---------------- K1: X_proj via f16 dot2, permuted cols (round-9, verified) ----------------
__global__ __launch_bounds__(256) void k_xproj(
  const float* __restrict__ X, const int* __restrict__ tgt,
  const uint* __restrict__ Wxpk, const float* __restrict__ blP,
  const float* __restrict__ offP, float* __restrict__ Xp)
{
  __shared__ uint As[8*72];
  __shared__ uint Bs[8*64];
  const int tid = threadIdx.x;
  const int m0 = blockIdx.x*64, j0 = blockIdx.y*64;
  const int tx = tid & 15, ty = tid >> 4;
  const int arow = tid >> 2, aseg = tid & 3;
  const int ma = m0 + arow;
  const float* Arow = X + ((ma & 255)*TT + (ma >> 8))*400;
  const int bkr = tid >> 5, bjs = tid & 31;
  float acc[4][4] = {};
  for (int k0 = 0; k0 < 400; k0 += 16){
    float4 av = *(const float4*)(Arow + k0 + aseg*4);
    uint2 bv = *(const uint2*)(Wxpk + (size_t)(k0/2 + bkr)*1024 + j0 + bjs*2);
    __syncthreads();
    As[(aseg*2+0)*72 + arow] = pkh(av.x, av.y);
    As[(aseg*2+1)*72 + arow] = pkh(av.z, av.w);
    *(uint2*)&Bs[bkr*64 + bjs*2] = bv;
    __syncthreads();
#pragma unroll
    for (int kk = 0; kk < 8; ++kk){
      uint4 a4 = *(const uint4*)&As[kk*72 + ty*4];
      uint4 b4 = *(const uint4*)&Bs[kk*64 + tx*4];
      acc[0][0]=dot2(b4.x,a4.x,acc[0][0]); acc[0][1]=dot2(b4.y,a4.x,acc[0][1]);
      acc[0][2]=dot2(b4.z,a4.x,acc[0][2]); acc[0][3]=dot2(b4.w,a4.x,acc[0][3]);
      acc[1][0]=dot2(b4.x,a4.y,acc[1][0]); acc[1][1]=dot2(b4.y,a4.y,acc[1][1]);
      acc[1][2]=dot2(b4.z,a4.y,acc[1][2]); acc[1][3]=dot2(b4.w,a4.y,acc[1][3]);
      acc[2][0]=dot2(b4.x,a4.z,acc[2][0]); acc[2][1]=dot2(b4.y,a4.z,acc[2][1]);
      acc[2][2]=dot2(b4.z,a4.z,acc[2][2]); acc[2][3]=dot2(b4.w,a4.z,acc[2][3]);
      acc[3][0]=dot2(b4.x,a4.w,acc[3][0]); acc[3][1]=dot2(b4.y,a4.w,acc[3][1]);
      acc[3][2]=dot2(b4.z,a4.w,acc[3][2]); acc[3][3]=dot2(b4.w,a4.w,acc[3][3]);
    }
  }
#pragma unroll
  for (int i = 0; i < 4; ++i){
    int m = m0 + ty*4 + i;
    int t = m >> 8, b = m & 255;
    int cj = j0 + tx*4;
    float4 bb = *(const float4*)&blP[cj];
    float4 r4 = make_float4(acc[i][0]+bb.x, acc[i][1]+bb.y, acc[i][2]+bb.z, acc[i][3]+bb.w);
    if (t > 0){
      int cls = tgt[b*TT + t - 1];
      float4 ov = *(const float4*)&offP[cls*1024 + cj];
      r4.x += ov.x; r4.y += ov.y; r4.z += ov.z; r4.w += ov.w;
    }
    *(float4*)&Xp[(size_t)m*1024 + cj] = r4;
  }
}

// B-side h-half GEMV chunk (waves 4-7): kp in [LO,HI) of Wpk rows 128..255.
// Block-scoped accumulator, flushed to ghL each region — nothing lives across barriers.
#define GHCHUNK0(LO, HI)                                                   \
  { float4 a = make_float4(0.f,0.f,0.f,0.f);                               \
    const uint* Wp = Wpk + (size_t)128*1024 + u*4;                         \
    _Pragma("unroll 8")                                                    \
    for (int kp = (LO); kp < (HI); ++kp){                                  \
      uint4 w4 = *(const uint4*)(Wp + (size_t)kp*1024);                    \
      uint vh = vH[128 + kp];                                              \
      a.x = dot2(w4.x, vh, a.x); a.y = dot2(w4.y, vh, a.y);                \
      a.z = dot2(w4.z, vh, a.z); a.w = dot2(w4.w, vh, a.w); }              \
    *(float4*)&ghL[u*4] = a; }

#define GHCHUNK(LO, HI)                                                    \
  { float4 a = make_float4(0.f,0.f,0.f,0.f);                               \
    const uint* Wp = Wpk + (size_t)128*1024 + u*4;                         \
    _Pragma("unroll 8")                                                    \
    for (int kp = (LO); kp < (HI); ++kp){                                  \
      uint4 w4 = *(const uint4*)(Wp + (size_t)kp*1024);                    \
      uint vh = vH[128 + kp];                                              \
      a.x = dot2(w4.x, vh, a.x); a.y = dot2(w4.y, vh, a.y);                \
      a.z = dot2(w4.z, vh, a.z); a.w = dot2(w4.w, vh, a.w); }              \
    float4 g = *(const float4*)&ghL[u*4];                                  \
    g.x += a.x; g.y += a.y; g.z += a.z; g.w += a.w;                        \
    *(float4*)&ghL[u*4] = g; }

// ---------------- K2: per-batch recurrent kernel; tail (waves 0-3) || h-GEMV(t+1) (waves 4-7) ----------------
__global__ __launch_bounds__(512, 2) void k_batch(
  const float* __restrict__ Xp, const uint* __restrict__ Wpk,
  const uint* __restrict__ Wkpu, const float4* __restrict__ Wa4,
  const float* __restrict__ bkp, const float* __restrict__ Wout,
  const float* __restrict__ bout, float* __restrict__ out)
{
  extern __shared__ float sm[];
  float* Ms    = sm;                  // 17408 (256 x 68)
  float* wrL   = sm + 17408;          // 1024
  float* simL  = wrL + 1024;          // 1024 (alpha partials R1/R2; sims R3/R4; pL cls4 R6/R7)
  float* scr   = simL + 1024;         // 1024 (R5 reads partials)
  float* pL    = scr + 1024;          // 1024 (logit partials cls 0-3)
  float* wuL   = pL + 1024;           // 256
  float* kL    = wuL + 256;           // 256
  float* WoutL = kL + 256;            // 2560
  float* waL   = WoutL + 2560;        // 1024
  float* bkpL  = waL + 1024;          // 264
  float* ghL   = bkpL + 264;          // 1024 (h-half gate accum for t+1)
  float* rgL   = ghL + 1024;          // 1024 (r-half gate accum for t+1)
  uint*  vH    = (uint*)(rgL + 1024); // 256 uints: [r pairs(128) | h pairs(128)]
  __shared__ int luS[4];
  __shared__ float alphaS[4];
  __shared__ float kinv[4];
  __shared__ float logitS[8];
  __shared__ float boutS[8];

  const int tid = threadIdx.x;
  const int b   = blockIdx.x;
  const int u   = tid & 255;

  // ---- init persistent per-batch state ----
#pragma unroll
  for (int it = 0; it < 32; ++it){
    int i = it*512 + tid;
    Ms[(i >> 6)*68 + (i & 63)] = 1e-6f;
  }
  wrL[tid] = 1.f/256.f; wrL[512+tid] = 1.f/256.f;
  ghL[tid] = 0.f; ghL[512+tid] = 0.f;
  rgL[tid] = 0.f; rgL[512+tid] = 0.f;
  if (tid < 256){ wuL[tid] = 1.f/256.f; vH[tid] = 0u; }
  for (int i = tid; i < 2560; i += 512) WoutL[i] = Wout[i];
  if (tid < 256) *(float4*)&waL[tid*4] = Wa4[tid];
  if (tid < 260) bkpL[tid] = bkp[tid];
  if (tid < 5) boutS[tid] = bout[tid];
  float creg = 0.f, hreg = 0.f;
  __syncthreads();

  for (int t = 0; t < TT; ++t){
    // ---- R0: combine gates + LSTM + h pack (threads 0-255) ----
    if (tid < 256){
      float4 xq = *(const float4*)(Xp + ((size_t)t*256 + b)*1024 + u*4);
      float4 gh = *(const float4*)&ghL[u*4];
      float4 gr = *(const float4*)&rgL[u*4];
      float gi = xq.x + gh.x + gr.x;
      float gf = xq.y + gh.y + gr.y;
      float gg = xq.z + gh.z + gr.z;
      float go = xq.w + gh.w + gr.w;
      creg = sigf(gf)*creg + sigf(gi)*tanhf(gg);
      hreg = sigf(go)*tanhf(creg);
      float ho = __shfl_xor(hreg, 1, 64);
      if (!(tid & 1)) vH[128 + (tid >> 1)] = pkh(hreg, ho);
    }
    __syncthreads();

    // ---- R1: A keyproj full-K + alpha partials | B h-chunk 0 (overwrite) ----
    if (tid < 256){
      float acc = 0.f;
      const uint* Wc = Wkpu + u;
#pragma unroll 4
      for (int i8 = 0; i8 < 128; i8 += 8){
        uint4 v0 = *(const uint4*)&vH[128 + i8];
        uint4 v1 = *(const uint4*)&vH[128 + i8 + 4];
        acc = dot2(Wc[(i8+0)*256], v0.x, acc);
        acc = dot2(Wc[(i8+1)*256], v0.y, acc);
        acc = dot2(Wc[(i8+2)*256], v0.z, acc);
        acc = dot2(Wc[(i8+3)*256], v0.w, acc);
        acc = dot2(Wc[(i8+4)*256], v1.x, acc);
        acc = dot2(Wc[(i8+5)*256], v1.y, acc);
        acc = dot2(Wc[(i8+6)*256], v1.z, acc);
        acc = dot2(Wc[(i8+7)*256], v1.w, acc);
      }
      kL[u] = tanhf(acc + bkpL[u]);
      float4 wa = *(const float4*)&waL[u*4];
      simL[u]     = hreg*wa.x;
      simL[256+u] = hreg*wa.y;
      simL[512+u] = hreg*wa.z;
      simL[768+u] = hreg*wa.w;
    } else { GHCHUNK0(0, 22) }
    __syncthreads();

    // ---- R2: A alpha+kinv reductions; wave0 top-4 argmin | B h-chunk ----
    if (tid < 256){
      const int w = tid >> 6, l = tid & 63;
      float s = simL[w*256+l] + simL[w*256+64+l] + simL[w*256+128+l] + simL[w*256+192+l];
      for (int o = 32; o; o >>= 1) s += __shfl_xor(s, o, 64);
      float kv = kL[w*64 + l];
      float sq = kv*kv;
      for (int o = 32; o; o >>= 1) sq += __shfl_xor(sq, o, 64);
      if (l == 0){
        alphaS[w] = sigf(s + bkpL[256 + w]);
        kinv[w]   = 1.f/(sqrtf(sq) + EPS_);
      }
      if (tid < 64){
        unsigned long long ks[4];
#pragma unroll
        for (int r = 0; r < 4; ++r){
          int idx = r*64 + tid;
          ks[r] = (((unsigned long long)__float_as_uint(wuL[idx])) << 32) | (unsigned)idx;
        }
#pragma unroll
        for (int round = 0; round < 4; ++round){
          unsigned long long m =
            ks[0] < ks[1] ? (ks[0] < ks[2] ? (ks[0] < ks[3] ? ks[0] : ks[3])
                                           : (ks[2] < ks[3] ? ks[2] : ks[3]))
                          : (ks[1] < ks[2] ? (ks[1] < ks[3] ? ks[1] : ks[3])
                                           : (ks[2] < ks[3] ? ks[2] : ks[3]));
          for (int o = 32; o; o >>= 1){
            unsigned long long other = __shfl_xor(m, o, 64);
            if (other < m) m = other;
          }
          if (tid == 0) luS[round] = (int)(unsigned)(m & 0xffffffffull);
#pragma unroll
          for (int r = 0; r < 4; ++r) if (ks[r] == m) ks[r] = ~0ull;
        }
      }
    } else { GHCHUNK(22, 43) }
    __syncthreads();

    // ---- R3: A M-update full-d + sims direct + wu=γwu+Σww | B h-chunk ----
    if (tid < 256){
      const int n = u;
      float a0 = alphaS[0], a1 = alphaS[1], a2 = alphaS[2], a3 = alphaS[3];
      float w0 = a0*wrL[n]     + ((n == luS[0]) ? (1.f - a0) : 0.f);
      float w1 = a1*wrL[256+n] + ((n == luS[1]) ? (1.f - a1) : 0.f);
      float w2 = a2*wrL[512+n] + ((n == luS[2]) ? (1.f - a2) : 0.f);
      float w3 = a3*wrL[768+n] + ((n == luS[3]) ? (1.f - a3) : 0.f);
      wuL[n] = GAMMA_*wuL[n] + (w0 + w1 + w2 + w3);
      const bool er = (n == luS[0]);
      float* row = Ms + n*68;
      float nsq = 0.f, s0 = 0.f, s1 = 0.f, s2 = 0.f, s3 = 0.f;
#pragma unroll
      for (int qq = 0; qq < 16; ++qq){
        const int dd = qq*4;
        float4 k0 = *(const float4*)&kL[      dd];
        float4 k1 = *(const float4*)&kL[ 64 + dd];
        float4 k2 = *(const float4*)&kL[128 + dd];
        float4 k3 = *(const float4*)&kL[192 + dd];
        float4 m4 = er ? make_float4(0.f,0.f,0.f,0.f) : *(const float4*)&row[dd];
        m4.x = fmaf(w0,k0.x, fmaf(w1,k1.x, fmaf(w2,k2.x, fmaf(w3,k3.x, m4.x))));
        m4.y = fmaf(w0,k0.y, fmaf(w1,k1.y, fmaf(w2,k2.y, fmaf(w3,k3.y, m4.y))));
        m4.z = fmaf(w0,k0.z, fmaf(w1,k1.z, fmaf(w2,k2.z, fmaf(w3,k3.z, m4.z))));
        m4.w = fmaf(w0,k0.w, fmaf(w1,k1.w, fmaf(w2,k2.w, fmaf(w3,k3.w, m4.w))));
        *(float4*)&row[dd] = m4;
        nsq = fmaf(m4.x,m4.x, fmaf(m4.y,m4.y, fmaf(m4.z,m4.z, fmaf(m4.w,m4.w, nsq))));
        s0 = fmaf(k0.x,m4.x, fmaf(k0.y,m4.y, fmaf(k0.z,m4.z, fmaf(k0.w,m4.w, s0))));
        s1 = fmaf(k1.x,m4.x, fmaf(k1.y,m4.y, fmaf(k1.z,m4.z, fmaf(k1.w,m4.w, s1))));
        s2 = fmaf(k2.x,m4.x, fmaf(k2.y,m4.y, fmaf(k2.z,m4.z, fmaf(k2.w,m4.w, s2))));
        s3 = fmaf(k3.x,m4.x, fmaf(k3.y,m4.y, fmaf(k3.z,m4.z, fmaf(k3.w,m4.w, s3))));
      }
      float minv = 1.f/(sqrtf(nsq) + EPS_);
      simL[n]     = s0 * kinv[0] * minv;
      simL[256+n] = s1 * kinv[1] * minv;
      simL[512+n] = s2 * kinv[2] * minv;
      simL[768+n] = s3 * kinv[3] * minv;
    } else { GHCHUNK(43, 64) }
    __syncthreads();

    // ---- R4: A softmax over slots | B h-chunk ----
    if (tid < 256){
      const int r = tid >> 6, l = tid & 63;
      float v0 = simL[r*256 + l],       v1 = simL[r*256 + 64 + l],
            v2 = simL[r*256 + 128 + l], v3 = simL[r*256 + 192 + l];
      float mx = fmaxf(fmaxf(v0,v1), fmaxf(v2,v3));
      for (int o = 32; o; o >>= 1) mx = fmaxf(mx, __shfl_xor(mx, o, 64));
      float e0 = expf(v0-mx), e1 = expf(v1-mx), e2 = expf(v2-mx), e3 = expf(v3-mx);
      float s = e0+e1+e2+e3;
      for (int o = 32; o; o >>= 1) s += __shfl_xor(s, o, 64);
      float inv = 1.f/s;
      wrL[r*256 + l] = e0*inv; wrL[r*256 + 64 + l] = e1*inv;
      wrL[r*256 + 128 + l] = e2*inv; wrL[r*256 + 192 + l] = e3*inv;
    } else { GHCHUNK(64, 86) }
    __syncthreads();

    // ---- R5: A reads partials (b128 broadcast rows, 4-way n-split) | B h-chunk ----
    if (tid < 256){
      const int s = tid >> 6, item = tid & 63;
      const int r = item >> 4, dq = item & 15;
      const float* wr = wrL + r*256;
      float4 a = make_float4(0.f,0.f,0.f,0.f);
#pragma unroll 8
      for (int i = 0; i < 64; ++i){
        int n = s*64 + i;
        float4 m4 = *(const float4*)&Ms[n*68 + dq*4];
        float wv = wr[n];
        a.x = fmaf(wv, m4.x, a.x); a.y = fmaf(wv, m4.y, a.y);
        a.z = fmaf(wv, m4.z, a.z); a.w = fmaf(wv, m4.w, a.w);
      }
      *(float4*)&scr[s*256 + item*4] = a;
    } else { GHCHUNK(86, 107) }
    __syncthreads();

    // ---- R6: A combine reads + r pack + wu += Σwr + logit partials | B last h-chunk ----
    if (tid < 256){
      float rv = scr[u] + scr[256+u] + scr[512+u] + scr[768+u];
      float ro = __shfl_xor(rv, 1, 64);
      if (!(tid & 1)) vH[tid >> 1] = pkh(rv, ro);
      wuL[u] += wrL[u] + wrL[256+u] + wrL[512+u] + wrL[768+u];
      const float* W1 = WoutL + u*5;
      const float* W2 = WoutL + (256+u)*5;
      float hv = hreg;
      pL[0*256+u] = hv*W1[0] + rv*W2[0];
      pL[1*256+u] = hv*W1[1] + rv*W2[1];
      pL[2*256+u] = hv*W1[2] + rv*W2[2];
      pL[3*256+u] = hv*W1[3] + rv*W2[3];
      simL[u]     = hv*W1[4] + rv*W2[4];    // class-4 partials (simL free after R4)
    } else { GHCHUNK(107, 128) }
    __syncthreads();

    // ---- R7: A logit reductions | B r-half GEMV(t+1) -> rgL ----
    if (tid < 256){
      const int w = tid >> 6, l = tid & 63;
      float s = pL[w*256+l] + pL[w*256+64+l] + pL[w*256+128+l] + pL[w*256+192+l];
      for (int o = 32; o; o >>= 1) s += __shfl_xor(s, o, 64);
      if (l == 0) logitS[w] = s + boutS[w];
      if (w == 0){
        float s4 = simL[l] + simL[64+l] + simL[128+l] + simL[192+l];
        for (int o = 32; o; o >>= 1) s4 += __shfl_xor(s4, o, 64);
        if (l == 0) logitS[4] = s4 + boutS[4];
      }
    } else {
      float4 a = make_float4(0.f,0.f,0.f,0.f);
      const uint* Wp = Wpk + u*4;           // r-half rows kp 0..127
#pragma unroll 8
      for (int kp = 0; kp < 128; ++kp){
        uint4 w4 = *(const uint4*)(Wp + (size_t)kp*1024);
        uint vh = vH[kp];
        a.x = dot2(w4.x, vh, a.x); a.y = dot2(w4.y, vh, a.y);
        a.z = dot2(w4.z, vh, a.z); a.w = dot2(w4.w, vh, a.w);
      }
      *(float4*)&rgL[u*4] = a;
    }
    __syncthreads();

    if (tid == 0){
      float l0 = logitS[0], l1 = logitS[1], l2 = logitS[2], l3 = logitS[3], l4 = logitS[4];
      float mx = fmaxf(fmaxf(fmaxf(l0,l1), fmaxf(l2,l3)), l4);
      float e0 = expf(l0-mx), e1 = expf(l1-mx), e2 = expf(l2-mx), e3 = expf(l3-mx), e4 = expf(l4-mx);
      float inv = 1.f/(e0+e1+e2+e3+e4);
      float* o5 = out + ((size_t)b*TT + t)*NCL;
      o5[0] = e0*inv; o5[1] = e1*inv; o5[2] = e2*inv; o5[3] = e3*inv; o5[4] = e4*inv;
    }
  }
}

extern "C" void kernel_launch(void* const* d_in, const int* in_sizes, int n_in,
                              void* d_out, int out_size, void* d_ws, size_t ws_size,
                              hipStream_t stream)
{
  (void)in_sizes; (void)n_in; (void)out_size; (void)ws_size;
  const float* X    = (const float*)d_in[0];
  const int*   tgt  = (const int*)d_in[1];
  const float* Wih  = (const float*)d_in[2];
  const float* Whh  = (const float*)d_in[3];
  const float* bl   = (const float*)d_in[4];
  const float* Wkp  = (const float*)d_in[5];
  const float* bkp  = (const float*)d_in[6];
  const float* Wout = (const float*)d_in[7];
  const float* bout = (const float*)d_in[8];
  float* out = (float*)d_out;

  float* Xp    = (float*)d_ws;              // 13,107,200 floats [T*B, 1024] unit-major
  uint*  Wpk   = (uint*)(Xp + 13107200);    // 262,144 uints
  uint*  Wkpu  = Wpk + 262144;              //  32,768 uints
  float4* Wa4  = (float4*)(Wkpu + 32768);   //     256 float4
  uint*  Wxpk  = (uint*)(Wa4 + 256);        // 204,800 uints
  float* blP   = (float*)(Wxpk + 204800);   //   1,024 floats
  float* offP  = blP + 1024;                //   5,120 floats

  hipFuncSetAttribute(reinterpret_cast<const void*>(k_batch),
                      hipFuncAttributeMaxDynamicSharedMemorySize, 112672);

  k_pack<<<1153, 256, 0, stream>>>(Wih, Whh, Wkp, Wpk, Wkpu, Wa4);
  k_pack2<<<824, 256, 0, stream>>>(Wih, bl, Wxpk, blP, offP);
  k_xproj<<<dim3(200,16), 256, 0, stream>>>(X, tgt, Wxpk, blP, offP, Xp);
  k_batch<<<256, 512, 112672, stream>>>(Xp, Wpk, Wkpu, Wa4, bkp, Wout, bout, out);
}

// Round 11
// 1011.862 us; speedup vs baseline: 4.9698x; 4.9698x over previous
//
#include <hip/hip_runtime.h>
#include <hip/hip_fp16.h>
#include <math.h>

#define TT 50
#define BB 256
#define HH 256
#define MSZ 256
#define MDM 64
#define NRD 4
#define NCL 5
#define GAMMA_ 0.95f
#define EPS_ 1e-8f

typedef unsigned int uint;

__device__ __forceinline__ float sigf(float x){ return 1.f/(1.f + expf(-x)); }

typedef _Float16 h2_t __attribute__((ext_vector_type(2)));

#if __has_builtin(__builtin_amdgcn_fdot2)
__device__ __forceinline__ float dot2(uint w, uint v, float c){
  return __builtin_amdgcn_fdot2(__builtin_bit_cast(h2_t, w),
                                __builtin_bit_cast(h2_t, v), c, false);
}
#else
__device__ __forceinline__ float dot2(uint w, uint v, float c){
  h2_t a = __builtin_bit_cast(h2_t, w), b = __builtin_bit_cast(h2_t, v);
  c = fmaf((float)a.x, (float)b.x, c);
  return fmaf((float)a.y, (float)b.y, c);
}
#endif

__device__ __forceinline__ uint pkh(float a, float b){
  uint lo = (uint)__half_as_ushort(__float2half_rn(a));
  uint hi = (uint)__half_as_ushort(__float2half_rn(b));
  return lo | (hi << 16);
}

// ---------------- K0: pack recurrent weights to f16 k-pairs (unit-major gate cols) ----------------
__global__ __launch_bounds__(256) void k_pack(
  const float* __restrict__ Wih, const float* __restrict__ Whh,
  const float* __restrict__ Wkp, uint* __restrict__ Wpk,
  uint* __restrict__ Wkpu, float4* __restrict__ Wa4)
{
  int i = blockIdx.x*256 + threadIdx.x;
  if (i < 262144){
    int kp = i >> 10, c = i & 1023;
    int u = c >> 2, g = c & 3;
    int cs = g*256 + u;
    int k0 = 2*kp, k1 = k0 + 1;
    float v0 = (k0 < 256) ? Wih[(405+k0)*1024 + cs] : Whh[(k0-256)*1024 + cs];
    float v1 = (k1 < 256) ? Wih[(405+k1)*1024 + cs] : Whh[(k1-256)*1024 + cs];
    Wpk[kp*1024 + c] = pkh(v0, v1);
  } else if (i < 294912){
    int j = i - 262144; int ip = j >> 8, jj = j & 255;
    Wkpu[ip*256 + jj] = pkh(Wkp[(2*ip)*260 + jj], Wkp[(2*ip+1)*260 + jj]);
  } else if (i < 295168){
    int j = i - 294912;
    const float* Wa = Wkp + j*260 + 256;
    Wa4[j] = make_float4(Wa[0], Wa[1], Wa[2], Wa[3]);
  }
}

// ---------------- K0b: pack W_ih[:400] to f16 k-pairs in PERMUTED col space; blP/offP ----------------
__global__ __launch_bounds__(256) void k_pack2(
  const float* __restrict__ Wih, const float* __restrict__ bl,
  uint* __restrict__ Wxpk, float* __restrict__ blP, float* __restrict__ offP)
{
  int i = blockIdx.x*256 + threadIdx.x;
  if (i < 204800){
    int kp = i >> 10, c = i & 1023;
    int cs = (c & 3)*256 + (c >> 2);
    Wxpk[i] = pkh(Wih[(2*kp)*1024 + cs], Wih[(2*kp+1)*1024 + cs]);
  } else if (i < 205824){
    int c = i - 204800;
    int cs = (c & 3)*256 + (c >> 2);
    blP[c] = bl[cs];
  } else if (i < 210944){
    int j = i - 205824;
    int cls = j >> 10, c = j & 1023;
    int cs = (c & 3)*256 + (c >> 2);
    offP[j] = Wih[(400+cls)*1024 + cs];
  }
}

// ---------------- K1: X_proj via f16 dot2, permuted cols; OUTPUT packed f16 pairs ----------------
__global__ __launch_bounds__(256) void k_xproj(
  const float* __restrict__ X, const int* __restrict__ tgt,
  const uint* __restrict__ Wxpk, const float* __restrict__ blP,
  const float* __restrict__ offP, uint* __restrict__ Xp2)
{
  __shared__ uint As[8*72];
  __shared__ uint Bs[8*64];
  const int tid = threadIdx.x;
  const int m0 = blockIdx.x*64, j0 = blockIdx.y*64;
  const int tx = tid & 15, ty = tid >> 4;
  const int arow = tid >> 2, aseg = tid & 3;
  const int ma = m0 + arow;
  const float* Arow = X + ((ma & 255)*TT + (ma >> 8))*400;
  const int bkr = tid >> 5, bjs = tid & 31;
  float acc[4][4] = {};
  for (int k0 = 0; k0 < 400; k0 += 16){
    float4 av = *(const float4*)(Arow + k0 + aseg*4);
    uint2 bv = *(const uint2*)(Wxpk + (size_t)(k0/2 + bkr)*1024 + j0 + bjs*2);
    __syncthreads();
    As[(aseg*2+0)*72 + arow] = pkh(av.x, av.y);
    As[(aseg*2+1)*72 + arow] = pkh(av.z, av.w);
    *(uint2*)&Bs[bkr*64 + bjs*2] = bv;
    __syncthreads();
#pragma unroll
    for (int kk = 0; kk < 8; ++kk){
      uint4 a4 = *(const uint4*)&As[kk*72 + ty*4];
      uint4 b4 = *(const uint4*)&Bs[kk*64 + tx*4];
      acc[0][0]=dot2(b4.x,a4.x,acc[0][0]); acc[0][1]=dot2(b4.y,a4.x,acc[0][1]);
      acc[0][2]=dot2(b4.z,a4.x,acc[0][2]); acc[0][3]=dot2(b4.w,a4.x,acc[0][3]);
      acc[1][0]=dot2(b4.x,a4.y,acc[1][0]); acc[1][1]=dot2(b4.y,a4.y,acc[1][1]);
      acc[1][2]=dot2(b4.z,a4.y,acc[1][2]); acc[1][3]=dot2(b4.w,a4.y,acc[1][3]);
      acc[2][0]=dot2(b4.x,a4.z,acc[2][0]); acc[2][1]=dot2(b4.y,a4.z,acc[2][1]);
      acc[2][2]=dot2(b4.z,a4.z,acc[2][2]); acc[2][3]=dot2(b4.w,a4.z,acc[2][3]);
      acc[3][0]=dot2(b4.x,a4.w,acc[3][0]); acc[3][1]=dot2(b4.y,a4.w,acc[3][1]);
      acc[3][2]=dot2(b4.z,a4.w,acc[3][2]); acc[3][3]=dot2(b4.w,a4.w,acc[3][3]);
    }
  }
#pragma unroll
  for (int i = 0; i < 4; ++i){
    int m = m0 + ty*4 + i;
    int t = m >> 8, b = m & 255;
    int cj = j0 + tx*4;
    float4 bb = *(const float4*)&blP[cj];
    float4 r4 = make_float4(acc[i][0]+bb.x, acc[i][1]+bb.y, acc[i][2]+bb.z, acc[i][3]+bb.w);
    if (t > 0){
      int cls = tgt[b*TT + t - 1];
      float4 ov = *(const float4*)&offP[cls*1024 + cj];
      r4.x += ov.x; r4.y += ov.y; r4.z += ov.z; r4.w += ov.w;
    }
    uint2 xo;
    xo.x = pkh(r4.x, r4.y);
    xo.y = pkh(r4.z, r4.w);
    *(uint2*)&Xp2[(size_t)m*512 + (cj >> 1)] = xo;
  }
}

// ---------------- K2: per-batch recurrent kernel, 512 threads, uniform structure, 9 barriers/step ----------------
__global__ __launch_bounds__(512, 2) void k_batch(
  const uint* __restrict__ Xp2, const uint* __restrict__ Wpk,
  const uint* __restrict__ Wkpu, const float4* __restrict__ Wa4,
  const float* __restrict__ bkp, const float* __restrict__ Wout,
  const float* __restrict__ bout, float* __restrict__ out)
{
  extern __shared__ float sm[];
  float* Ms    = sm;                  // 17408 (256 x 68)
  float* wrL   = sm + 17408;          // 1024
  float* simL  = wrL + 1024;          // 1024 (alpha partials; class-4 logit partials)
  float* scr   = simL + 1024;         // 2560 (GEMV partials / keyproj / M-update / reads)
  float* pLw   = scr + 2560;          // 1024 (logit partials cls 0-3; old wwL slot)
  float* wuL   = pLw + 1024;          // 256
  float* kL    = wuL + 256;           // 256
  float* WoutL = kL + 256;            // 2560
  float* waL   = WoutL + 2560;        // 1024
  float* bkpL  = waL + 1024;          // 264
  uint*  vH    = (uint*)(bkpL + 264); // 256 uints: [r pairs(128) | h pairs(128)]
  __shared__ int luS[4];
  __shared__ float alphaS[4];
  __shared__ float kinv[4];
  __shared__ float logitS[8];
  __shared__ float boutS[8];

  const int tid = threadIdx.x;
  const int b   = blockIdx.x;
  const int u   = tid & 255;
  const int q   = tid >> 8;

  // ---- init persistent per-batch state ----
#pragma unroll
  for (int it = 0; it < 32; ++it){
    int i = it*512 + tid;
    Ms[(i >> 6)*68 + (i & 63)] = 1e-6f;
  }
  wrL[tid] = 1.f/256.f; wrL[512+tid] = 1.f/256.f;
  if (tid < 256){ wuL[tid] = 1.f/256.f; vH[tid] = 0u; }
  for (int i = tid; i < 2560; i += 512) WoutL[i] = Wout[i];
  if (tid < 256) *(float4*)&waL[tid*4] = Wa4[tid];
  if (tid < 260) bkpL[tid] = bkp[tid];
  if (tid < 5) boutS[tid] = bout[tid];
  float creg = 0.f, hreg = 0.f;
  __syncthreads();

  for (int t = 0; t < TT; ++t){
    // ---- P1: gate GEMV partials (f16 dot2, 2-way K-split over [r|h]) + xq prefetch ----
    uint2 xq;
    if (tid < 256) xq = *(const uint2*)(Xp2 + ((size_t)t*256 + b)*512 + u*2);
    {
      const uint* Wp = Wpk + (size_t)(q*128)*1024 + u*4;
      float4 acc4 = make_float4(0.f, 0.f, 0.f, 0.f);
      for (int kp8 = 0; kp8 < 128; kp8 += 8){
        uint4 vh0 = *(const uint4*)&vH[q*128 + kp8];
        uint4 vh1 = *(const uint4*)&vH[q*128 + kp8 + 4];
        const uint* wb = Wp + (size_t)kp8*1024;
        uint4 q0 = *(const uint4*)(wb + 0*1024);
        uint4 q1 = *(const uint4*)(wb + 1*1024);
        uint4 q2 = *(const uint4*)(wb + 2*1024);
        uint4 q3 = *(const uint4*)(wb + 3*1024);
        uint4 q4 = *(const uint4*)(wb + 4*1024);
        uint4 q5 = *(const uint4*)(wb + 5*1024);
        uint4 q6 = *(const uint4*)(wb + 6*1024);
        uint4 q7 = *(const uint4*)(wb + 7*1024);
        acc4.x = dot2(q0.x, vh0.x, acc4.x); acc4.y = dot2(q0.y, vh0.x, acc4.y);
        acc4.z = dot2(q0.z, vh0.x, acc4.z); acc4.w = dot2(q0.w, vh0.x, acc4.w);
        acc4.x = dot2(q1.x, vh0.y, acc4.x); acc4.y = dot2(q1.y, vh0.y, acc4.y);
        acc4.z = dot2(q1.z, vh0.y, acc4.z); acc4.w = dot2(q1.w, vh0.y, acc4.w);
        acc4.x = dot2(q2.x, vh0.z, acc4.x); acc4.y = dot2(q2.y, vh0.z, acc4.y);
        acc4.z = dot2(q2.z, vh0.z, acc4.z); acc4.w = dot2(q2.w, vh0.z, acc4.w);
        acc4.x = dot2(q3.x, vh0.w, acc4.x); acc4.y = dot2(q3.y, vh0.w, acc4.y);
        acc4.z = dot2(q3.z, vh0.w, acc4.z); acc4.w = dot2(q3.w, vh0.w, acc4.w);
        acc4.x = dot2(q4.x, vh1.x, acc4.x); acc4.y = dot2(q4.y, vh1.x, acc4.y);
        acc4.z = dot2(q4.z, vh1.x, acc4.z); acc4.w = dot2(q4.w, vh1.x, acc4.w);
        acc4.x = dot2(q5.x, vh1.y, acc4.x); acc4.y = dot2(q5.y, vh1.y, acc4.y);
        acc4.z = dot2(q5.z, vh1.y, acc4.z); acc4.w = dot2(q5.w, vh1.y, acc4.w);
        acc4.x = dot2(q6.x, vh1.z, acc4.x); acc4.y = dot2(q6.y, vh1.z, acc4.y);
        acc4.z = dot2(q6.z, vh1.z, acc4.z); acc4.w = dot2(q6.w, vh1.z, acc4.w);
        acc4.x = dot2(q7.x, vh1.w, acc4.x); acc4.y = dot2(q7.y, vh1.w, acc4.y);
        acc4.z = dot2(q7.z, vh1.w, acc4.z); acc4.w = dot2(q7.w, vh1.w, acc4.w);
      }
      *(float4*)&scr[q*1024 + u*4] = acc4;
    }
    __syncthreads();

    // ---- P2+3: combine gates (+ f16 Xp unpack) + LSTM + h pack ----
    if (tid < 256){
      float4 p0 = *(const float4*)&scr[        u*4];
      float4 p1 = *(const float4*)&scr[1024 + u*4];
      h2_t xa = __builtin_bit_cast(h2_t, xq.x);
      h2_t xb = __builtin_bit_cast(h2_t, xq.y);
      float gi = (float)xa.x + p0.x + p1.x;
      float gf = (float)xa.y + p0.y + p1.y;
      float gg = (float)xb.x + p0.z + p1.z;
      float go = (float)xb.y + p0.w + p1.w;
      creg = sigf(gf)*creg + sigf(gi)*tanhf(gg);
      hreg = sigf(go)*tanhf(creg);
      float ho = __shfl_xor(hreg, 1, 64);
      if (!(tid & 1)) vH[128 + (tid >> 1)] = pkh(hreg, ho);
    }
    __syncthreads();

    // ---- P4: key projection partials (f16 dot2, 2-way K-split) + alpha partials ----
    {
      const uint* Wc = Wkpu + (size_t)(q*64)*256 + u;
      float acc = 0.f;
#pragma unroll 8
      for (int ii = 0; ii < 64; ++ii)
        acc = dot2(Wc[ii*256], vH[128 + q*64 + ii], acc);
      scr[q*256 + u] = acc;
    }
    if (tid < 256){
      float4 wa = *(const float4*)&waL[tid*4];
      simL[tid]     = hreg*wa.x;
      simL[256+tid] = hreg*wa.y;
      simL[512+tid] = hreg*wa.z;
      simL[768+tid] = hreg*wa.w;
    }
    __syncthreads();

    // ---- P5+6+7: finish keys; alpha + kinv; wave-0 register top-4 argmin ----
    if (tid < 256){
      float kv = tanhf(scr[tid] + scr[256+tid] + bkpL[tid]);
      kL[tid] = kv;
      const int w = tid >> 6, l = tid & 63;
      float s = simL[w*256+l] + simL[w*256+64+l] + simL[w*256+128+l] + simL[w*256+192+l];
      for (int o = 32; o; o >>= 1) s += __shfl_xor(s, o, 64);
      float sq = kv*kv;
      for (int o = 32; o; o >>= 1) sq += __shfl_xor(sq, o, 64);
      if (l == 0){
        alphaS[w] = sigf(s + bkpL[256 + w]);
        kinv[w]   = 1.f/(sqrtf(sq) + EPS_);
      }
    }
    if (tid < 64){
      unsigned long long ks[4];
#pragma unroll
      for (int r = 0; r < 4; ++r){
        int idx = r*64 + tid;
        ks[r] = (((unsigned long long)__float_as_uint(wuL[idx])) << 32) | (unsigned)idx;
      }
#pragma unroll
      for (int round = 0; round < 4; ++round){
        unsigned long long m =
          ks[0] < ks[1] ? (ks[0] < ks[2] ? (ks[0] < ks[3] ? ks[0] : ks[3])
                                         : (ks[2] < ks[3] ? ks[2] : ks[3]))
                        : (ks[1] < ks[2] ? (ks[1] < ks[3] ? ks[1] : ks[3])
                                         : (ks[2] < ks[3] ? ks[2] : ks[3]));
        for (int o = 32; o; o >>= 1){
          unsigned long long other = __shfl_xor(m, o, 64);
          if (other < m) m = other;
        }
        if (tid == 0) luS[round] = (int)(unsigned)(m & 0xffffffffull);
#pragma unroll
        for (int r = 0; r < 4; ++r) if (ks[r] == m) ks[r] = ~0ull;
      }
    }
    __syncthreads();

    // ---- P8+9: write-weights inline; erase lu0; M += w k^T; wu = γwu+Σww; norm+sim partials ----
    {
      const int n = u, d0 = q*32;
      float a0 = alphaS[0], a1 = alphaS[1], a2 = alphaS[2], a3 = alphaS[3];
      float w0 = a0*wrL[n]     + ((n == luS[0]) ? (1.f - a0) : 0.f);
      float w1 = a1*wrL[256+n] + ((n == luS[1]) ? (1.f - a1) : 0.f);
      float w2 = a2*wrL[512+n] + ((n == luS[2]) ? (1.f - a2) : 0.f);
      float w3 = a3*wrL[768+n] + ((n == luS[3]) ? (1.f - a3) : 0.f);
      if (q == 0) wuL[n] = GAMMA_*wuL[n] + (w0 + w1 + w2 + w3);
      const bool er = (n == luS[0]);
      float* row = Ms + n*68 + d0;
      float nsq = 0.f, s0 = 0.f, s1 = 0.f, s2 = 0.f, s3 = 0.f;
#pragma unroll
      for (int qq = 0; qq < 8; ++qq){
        const int dd = qq*4;
        float4 k0 = *(const float4*)&kL[      d0 + dd];
        float4 k1 = *(const float4*)&kL[ 64 + d0 + dd];
        float4 k2 = *(const float4*)&kL[128 + d0 + dd];
        float4 k3 = *(const float4*)&kL[192 + d0 + dd];
        float4 m4 = er ? make_float4(0.f,0.f,0.f,0.f) : *(const float4*)&row[dd];
        m4.x = fmaf(w0,k0.x, fmaf(w1,k1.x, fmaf(w2,k2.x, fmaf(w3,k3.x, m4.x))));
        m4.y = fmaf(w0,k0.y, fmaf(w1,k1.y, fmaf(w2,k2.y, fmaf(w3,k3.y, m4.y))));
        m4.z = fmaf(w0,k0.z, fmaf(w1,k1.z, fmaf(w2,k2.z, fmaf(w3,k3.z, m4.z))));
        m4.w = fmaf(w0,k0.w, fmaf(w1,k1.w, fmaf(w2,k2.w, fmaf(w3,k3.w, m4.w))));
        *(float4*)&row[dd] = m4;
        nsq = fmaf(m4.x,m4.x, fmaf(m4.y,m4.y, fmaf(m4.z,m4.z, fmaf(m4.w,m4.w, nsq))));
        s0 = fmaf(k0.x,m4.x, fmaf(k0.y,m4.y, fmaf(k0.z,m4.z, fmaf(k0.w,m4.w, s0))));
        s1 = fmaf(k1.x,m4.x, fmaf(k1.y,m4.y, fmaf(k1.z,m4.z, fmaf(k1.w,m4.w, s1))));
        s2 = fmaf(k2.x,m4.x, fmaf(k2.y,m4.y, fmaf(k2.z,m4.z, fmaf(k2.w,m4.w, s2))));
        s3 = fmaf(k3.x,m4.x, fmaf(k3.y,m4.y, fmaf(k3.z,m4.z, fmaf(k3.w,m4.w, s3))));
      }
      scr[       q*256 + n] = nsq;
      scr[512  + q*256 + n] = s0;
      scr[1024 + q*256 + n] = s1;
      scr[1536 + q*256 + n] = s2;
      scr[2048 + q*256 + n] = s3;
    }
    __syncthreads();

    // ---- P11m: merged norm-combine + softmax (one wave per read head) ----
    if (tid < 256){
      const int r = tid >> 6, l = tid & 63;
      float v[4];
#pragma unroll
      for (int j = 0; j < 4; ++j){
        int n = j*64 + l;
        float nsq = scr[n] + scr[256+n];
        float minv = 1.f/(sqrtf(nsq) + EPS_);
        float sv = scr[512 + 512*r + n] + scr[768 + 512*r + n];
        v[j] = sv * kinv[r] * minv;
      }
      float mx = fmaxf(fmaxf(v[0],v[1]), fmaxf(v[2],v[3]));
      for (int o = 32; o; o >>= 1) mx = fmaxf(mx, __shfl_xor(mx, o, 64));
      float e0 = expf(v[0]-mx), e1 = expf(v[1]-mx), e2 = expf(v[2]-mx), e3 = expf(v[3]-mx);
      float s = e0+e1+e2+e3;
      for (int o = 32; o; o >>= 1) s += __shfl_xor(s, o, 64);
      float inv = 1.f/s;
      wrL[r*256 + l] = e0*inv; wrL[r*256 + 64 + l] = e1*inv;
      wrL[r*256 + 128 + l] = e2*inv; wrL[r*256 + 192 + l] = e3*inv;
    }
    __syncthreads();

    // ---- P12: reads partials = w_r @ M (b128 broadcast rows, 8-way n-split, all 512 thr) ----
    {
      const int s = tid >> 6, item = tid & 63;
      const int r = item >> 4, dq = item & 15;
      const float* wr = wrL + r*256;
      float4 a = make_float4(0.f,0.f,0.f,0.f);
#pragma unroll 8
      for (int i = 0; i < 32; ++i){
        int n = s*32 + i;
        float4 m4 = *(const float4*)&Ms[n*68 + dq*4];
        float wv = wr[n];
        a.x = fmaf(wv, m4.x, a.x); a.y = fmaf(wv, m4.y, a.y);
        a.z = fmaf(wv, m4.z, a.z); a.w = fmaf(wv, m4.w, a.w);
      }
      *(float4*)&scr[s*256 + item*4] = a;
    }
    __syncthreads();

    // ---- P13: combine reads + r pack; wu += Σwr; logit partials (pLw/simL, no scr alias) ----
    if (tid < 256){
      float rv = scr[tid]      + scr[256+tid]  + scr[512+tid]  + scr[768+tid]
               + scr[1024+tid] + scr[1280+tid] + scr[1536+tid] + scr[1792+tid];
      float ro = __shfl_xor(rv, 1, 64);
      if (!(tid & 1)) vH[tid >> 1] = pkh(rv, ro);
      wuL[tid] += wrL[tid] + wrL[256+tid] + wrL[512+tid] + wrL[768+tid];
      const float* W1 = WoutL + tid*5;
      const float* W2 = WoutL + (256+tid)*5;
      float hv = hreg;
      pLw[0*256+tid] = hv*W1[0] + rv*W2[0];
      pLw[1*256+tid] = hv*W1[1] + rv*W2[1];
      pLw[2*256+tid] = hv*W1[2] + rv*W2[2];
      pLw[3*256+tid] = hv*W1[3] + rv*W2[3];
      simL[tid]      = hv*W1[4] + rv*W2[4];
    }
    __syncthreads();

    // ---- P14: logit reductions ----
    if (tid < 256){
      const int w = tid >> 6, l = tid & 63;
      float s = pLw[w*256+l] + pLw[w*256+64+l] + pLw[w*256+128+l] + pLw[w*256+192+l];
      for (int o = 32; o; o >>= 1) s += __shfl_xor(s, o, 64);
      if (l == 0) logitS[w] = s + boutS[w];
      if (w == 0){
        float s4 = simL[l] + simL[64+l] + simL[128+l] + simL[192+l];
        for (int o = 32; o; o >>= 1) s4 += __shfl_xor(s4, o, 64);
        if (l == 0) logitS[4] = s4 + boutS[4];
      }
    }
    __syncthreads();
    if (tid == 0){
      float l0 = logitS[0], l1 = logitS[1], l2 = logitS[2], l3 = logitS[3], l4 = logitS[4];
      float mx = fmaxf(fmaxf(fmaxf(l0,l1), fmaxf(l2,l3)), l4);
      float e0 = expf(l0-mx), e1 = expf(l1-mx), e2 = expf(l2-mx), e3 = expf(l3-mx), e4 = expf(l4-mx);
      float inv = 1.f/(e0+e1+e2+e3+e4);
      float* o5 = out + ((size_t)b*TT + t)*NCL;
      o5[0] = e0*inv; o5[1] = e1*inv; o5[2] = e2*inv; o5[3] = e3*inv; o5[4] = e4*inv;
    }
    // no end-of-loop barrier: P1 writes scr (disjoint from pLw/simL/logitS readers),
    // and every later consumer is separated by at least one barrier.
  }
}

extern "C" void kernel_launch(void* const* d_in, const int* in_sizes, int n_in,
                              void* d_out, int out_size, void* d_ws, size_t ws_size,
                              hipStream_t stream)
{
  (void)in_sizes; (void)n_in; (void)out_size; (void)ws_size;
  const float* X    = (const float*)d_in[0];
  const int*   tgt  = (const int*)d_in[1];
  const float* Wih  = (const float*)d_in[2];
  const float* Whh  = (const float*)d_in[3];
  const float* bl   = (const float*)d_in[4];
  const float* Wkp  = (const float*)d_in[5];
  const float* bkp  = (const float*)d_in[6];
  const float* Wout = (const float*)d_in[7];
  const float* bout = (const float*)d_in[8];
  float* out = (float*)d_out;

  uint*  Xp2   = (uint*)d_ws;               // 6,553,600 uints [T*B, 512] f16 pairs, unit-major
  uint*  Wpk   = Xp2 + 6553600;             // 262,144 uints
  uint*  Wkpu  = Wpk + 262144;              //  32,768 uints
  float4* Wa4  = (float4*)(Wkpu + 32768);   //     256 float4
  uint*  Wxpk  = (uint*)(Wa4 + 256);        // 204,800 uints
  float* blP   = (float*)(Wxpk + 204800);   //   1,024 floats
  float* offP  = blP + 1024;                //   5,120 floats

  hipFuncSetAttribute(reinterpret_cast<const void*>(k_batch),
                      hipFuncAttributeMaxDynamicSharedMemorySize, 110624);

  k_pack<<<1153, 256, 0, stream>>>(Wih, Whh, Wkp, Wpk, Wkpu, Wa4);
  k_pack2<<<824, 256, 0, stream>>>(Wih, bl, Wxpk, blP, offP);
  k_xproj<<<dim3(200,16), 256, 0, stream>>>(X, tgt, Wxpk, blP, offP, Xp2);
  k_batch<<<256, 512, 110624, stream>>>(Xp2, Wpk, Wkpu, Wa4, bkp, Wout, bout, out);
}